// Round 15
// baseline (237.370 us; speedup 1.0000x reference)
//
#include <hip/hip_runtime.h>

// VQ-VAE quantizer: z [16,4096,64] f32, embedding [1024,64] f32.
// Outputs concatenated in d_out (float32): [0]=loss, [1..4194304]=z_q,
// [4194305..]=argmin indices (as float).
//
// Correctness-critical (verified absmax 0.0 through R14): per-(row,code)
// d = fmaf(-2,dot,(zz+ee)); dot accumulated as p0..p3 (acc.xyzw) over 16
// float4 chunks combined (p0+p1)+(p2+p3); zz/ee numpy-pairwise 8-accumulator
// tree, fp-contract OFF; first-index argmin via strict < on in-lane ascending
// scans + (val==, idx<) tie-break on every tree merge (idx-aware merges are
// order-independent). Loss: per-row sequential col sum + 64-lane shfl tree +
// one atomic per 64-row group (R13-verified grouping).
//
// R15 change: DOUBLE BLOCK, SAME PER-WAVE TILE (attack barrier-drain). R11's
// plateau: LDS model 128us vs measured 174us; R12/R13/R14 eliminated pipe-
// split, fat-tile, and address-VALU as explanations. Remaining lever:
// R11 runs 2 waves/SIMD with 64 barrier-drain events/CU. Fix: ROWS=128,
// TPB=512 (8 waves = 2 row-halves x 4 code-quarters), each wave = R11's
// exact 8r x 4c tile over TCODES=128. Barriers/CU halve (2 blocks x 16);
// waves/SIMD double to 4 (per-lane state shrinks: pe[8]->pe[4]); LDS-op
// total unchanged. LDS = z 32K + e 32K = 64KB exactly; zz transits via
// e_lds pre-loop (R13-verified); smv/smi alias dead z_lds post-loop;
// epilogue reads z from global (R12/R13-verified identical bits); ee per
// tile from the 4KB L1-hot ee_ws into 4 regs during the prefetch phase.

#define D 64
#define NE 1024
#define ROWS 128             // rows per block
#define TCODES 128           // codes per LDS tile
#define NTILES 8
#define TPB 512              // 8 waves = 2 row-halves x 4 code-quarters

// swizzled float index of (row, f4col c): row*64 + (c^(row&7))*4
#define SWZ(row, c) (((row) << 6) + ((((c) ^ ((row) & 7))) << 2))

__global__ __launch_bounds__(64, 4) void ee_kernel(const float* __restrict__ emb,
                                                   float* __restrict__ ee_ws) {
    const int j = blockIdx.x * 64 + threadIdx.x;   // 16 blocks x 64 = 1024 codes
    {
#pragma clang fp contract(off)
        const float4* e4 = (const float4*)(emb + ((size_t)j << 6));
        float4 a = e4[0], b = e4[1];
        float r[8];
        r[0]=a.x*a.x; r[1]=a.y*a.y; r[2]=a.z*a.z; r[3]=a.w*a.w;
        r[4]=b.x*b.x; r[5]=b.y*b.y; r[6]=b.z*b.z; r[7]=b.w*b.w;
#pragma unroll
        for (int g = 1; g < 8; ++g) {
            float4 c = e4[2*g], e = e4[2*g + 1];
            r[0]=r[0]+c.x*c.x; r[1]=r[1]+c.y*c.y;
            r[2]=r[2]+c.z*c.z; r[3]=r[3]+c.w*c.w;
            r[4]=r[4]+e.x*e.x; r[5]=r[5]+e.y*e.y;
            r[6]=r[6]+e.z*e.z; r[7]=r[7]+e.w*e.w;
        }
        ee_ws[j] = ((r[0]+r[1])+(r[2]+r[3])) + ((r[4]+r[5])+(r[6]+r[7]));
    }
}

__global__ __launch_bounds__(TPB, 2) void vq_kernel(const float* __restrict__ z,
                                                    const float* __restrict__ emb,
                                                    const float* __restrict__ ee_ws,
                                                    float* __restrict__ out_loss,
                                                    float* __restrict__ out_zq,
                                                    float* __restrict__ out_idx,
                                                    float loss_scale) {
    __shared__ __align__(16) float z_lds[ROWS * D];     // 32 KB
    __shared__ __align__(16) float e_lds[TCODES * D];   // 32 KB (total = 64 KB)

    const int tid  = threadIdx.x;
    const int lane = tid & 63;
    const int w    = tid >> 6;          // 8 waves
    const int rh   = w & 1;             // row half: rows [64rh, 64rh+64)
    const int cq   = w >> 1;            // code quarter of each 128-code tile
    const int i8   = lane & 7;          // row group: rows 64rh + i8 + 8rr
    const int jg   = lane >> 3;         // code group: codes 32cq + jg + 8cc
    const size_t blockRow = (size_t)blockIdx.x * ROWS;
    const int zrow0 = (rh << 6) + i8;

    // --- Stage z tile (128x64) into swizzled LDS (2048 f4, 4/thread). ---
    {
        const float4* zg4 = (const float4*)(z + blockRow * D);
#pragma unroll
        for (int k = 0; k < 4; ++k) {
            int idx = tid + k * TPB;
            float4 v = zg4[idx];
            *(float4*)&z_lds[SWZ(idx >> 4, idx & 15)] = v;
        }
    }

    // --- zz per row from GLOBAL z (R12/R13-verified pattern; identical bits),
    //     staged transiently in e_lds[0..127] before tile 0 overwrites. ---
    if (tid < ROWS) {
        float zr[D];
        const float4* zrow4 = (const float4*)(z + (blockRow + tid) * D);
#pragma unroll
        for (int c = 0; c < 16; ++c) {
            float4 v = zrow4[c];
            zr[4*c+0]=v.x; zr[4*c+1]=v.y; zr[4*c+2]=v.z; zr[4*c+3]=v.w;
        }
        {
#pragma clang fp contract(off)
            float r[8];
#pragma unroll
            for (int jj = 0; jj < 8; ++jj) { float t = zr[jj]*zr[jj]; r[jj] = t; }
#pragma unroll
            for (int i = 8; i < 64; i += 8) {
#pragma unroll
                for (int jj = 0; jj < 8; ++jj) { float t = zr[i+jj]*zr[i+jj]; r[jj] = r[jj] + t; }
            }
            e_lds[tid] = ((r[0]+r[1])+(r[2]+r[3])) + ((r[4]+r[5])+(r[6]+r[7]));
        }
    }
    __syncthreads();                     // z_lds staged, zz visible
    float zzr[8];
#pragma unroll
    for (int rr = 0; rr < 8; ++rr) zzr[rr] = e_lds[zrow0 + 8*rr];
    __syncthreads();                     // zz reads done; e_lds free for tiles

    // --- Prefetch e-tile 0 into registers (2048 f4, 4/thread). ---
    float4 pe0, pe1, pe2, pe3;
    {
        const float4* eg4 = (const float4*)emb;
        pe0 = eg4[tid];        pe1 = eg4[tid + TPB];
        pe2 = eg4[tid + 2*TPB]; pe3 = eg4[tid + 3*TPB];
    }
    float eev0, eev1, eev2, eev3;
    {
        const int cb0 = (cq << 5) + jg;
        eev0 = ee_ws[cb0]; eev1 = ee_ws[cb0 + 8];
        eev2 = ee_ws[cb0 + 16]; eev3 = ee_ws[cb0 + 24];
    }

    float rb[8];  int rbj[8];
#pragma unroll
    for (int rr = 0; rr < 8; ++rr) { rb[rr] = __builtin_inff(); rbj[rr] = 0; }

    // --- Main loop: 8 tiles of 128 codes; 2 barriers/tile. ---
    for (int t = 0; t < NTILES; ++t) {
        // Write prefetched tile t into LDS.
        *(float4*)&e_lds[SWZ((tid          ) >> 4, (tid          ) & 15)] = pe0;
        *(float4*)&e_lds[SWZ((tid +    TPB ) >> 4, (tid +    TPB ) & 15)] = pe1;
        *(float4*)&e_lds[SWZ((tid +  2*TPB ) >> 4, (tid +  2*TPB ) & 15)] = pe2;
        *(float4*)&e_lds[SWZ((tid +  3*TPB ) >> 4, (tid +  3*TPB ) & 15)] = pe3;
        __syncthreads();   // e tile t ready

        const int cbase = t * TCODES + (cq << 5) + jg;
        const float ee0 = eev0, ee1 = eev1, ee2 = eev2, ee3 = eev3;

        // Issue prefetch of tile t+1 (+ its ee); hides under compute of tile t.
        if (t < NTILES - 1) {
            const float4* eg4 = (const float4*)(emb + (size_t)(t + 1) * TCODES * D);
            pe0 = eg4[tid];         pe1 = eg4[tid + TPB];
            pe2 = eg4[tid + 2*TPB]; pe3 = eg4[tid + 3*TPB];
            const int cbn = (t + 1) * TCODES + (cq << 5) + jg;
            eev0 = ee_ws[cbn]; eev1 = ee_ws[cbn + 8];
            eev2 = ee_ws[cbn + 16]; eev3 = ee_ws[cbn + 24];
        }

        // 8 rows x 4 codes per lane; p0..p3 live in acc.{x,y,z,w} (verified order).
        float4 acc[8][4];
#pragma unroll
        for (int rr = 0; rr < 8; ++rr)
#pragma unroll
            for (int cc = 0; cc < 4; ++cc)
                acc[rr][cc] = make_float4(0.f, 0.f, 0.f, 0.f);

#pragma unroll 2
        for (int c = 0; c < 16; ++c) {
            float4 zf[8], ef[4];
#pragma unroll
            for (int rr = 0; rr < 8; ++rr)
                zf[rr] = *(const float4*)&z_lds[SWZ(zrow0 + 8*rr, c)];
#pragma unroll
            for (int cc = 0; cc < 4; ++cc)
                ef[cc] = *(const float4*)&e_lds[SWZ((cq << 5) + jg + (cc << 3), c)];
#pragma unroll
            for (int rr = 0; rr < 8; ++rr)
#pragma unroll
                for (int cc = 0; cc < 4; ++cc) {
                    acc[rr][cc].x = fmaf(zf[rr].x, ef[cc].x, acc[rr][cc].x);
                    acc[rr][cc].y = fmaf(zf[rr].y, ef[cc].y, acc[rr][cc].y);
                    acc[rr][cc].z = fmaf(zf[rr].z, ef[cc].z, acc[rr][cc].z);
                    acc[rr][cc].w = fmaf(zf[rr].w, ef[cc].w, acc[rr][cc].w);
                }
        }

        // Fold: codes cbase + 8cc ascend with cc; tiles ascend with t -> strict <.
#pragma unroll
        for (int rr = 0; rr < 8; ++rr) {
            const float zzv = zzr[rr];
            float dot0 = (acc[rr][0].x + acc[rr][0].y) + (acc[rr][0].z + acc[rr][0].w);
            float dot1 = (acc[rr][1].x + acc[rr][1].y) + (acc[rr][1].z + acc[rr][1].w);
            float dot2 = (acc[rr][2].x + acc[rr][2].y) + (acc[rr][2].z + acc[rr][2].w);
            float dot3 = (acc[rr][3].x + acc[rr][3].y) + (acc[rr][3].z + acc[rr][3].w);
            float d0 = fmaf(-2.0f, dot0, zzv + ee0);   // mirrors np (zz+ee) rounding
            float d1 = fmaf(-2.0f, dot1, zzv + ee1);
            float d2 = fmaf(-2.0f, dot2, zzv + ee2);
            float d3 = fmaf(-2.0f, dot3, zzv + ee3);
            float cv = d0; int cj = cbase;
            if (d1 < cv) { cv = d1; cj = cbase + 8;  }
            if (d2 < cv) { cv = d2; cj = cbase + 16; }
            if (d3 < cv) { cv = d3; cj = cbase + 24; }
            if (cv < rb[rr]) { rb[rr] = cv; rbj[rr] = cj; }
        }
        __syncthreads();   // all reads of e_lds done before next overwrite
    }

    // --- 3-step butterfly over jg (lane bits 3..5): tie -> smaller index.
    //     Partials into z_lds alias (z_lds dead: epilogue reads z global). ---
    float* smv = z_lds;                  // [4][128] floats
    int*   smi = (int*)(z_lds + 4 * ROWS);
#pragma unroll
    for (int rr = 0; rr < 8; ++rr) {
        float bv = rb[rr]; int bj = rbj[rr];
#pragma unroll
        for (int off = 8; off <= 32; off <<= 1) {
            float ov = __shfl_xor(bv, off);
            int   oi = __shfl_xor(bj, off);
            if (ov < bv || (ov == bv && oi < bj)) { bv = ov; bj = oi; }
        }
        if (jg == 0) {
            smv[cq * ROWS + zrow0 + 8*rr] = bv;
            smi[cq * ROWS + zrow0 + 8*rr] = bj;
        }
    }
    __syncthreads();

    // --- Epilogue (R13-verified structure): thread handles row erow; group eg
    //     stores f4-chunks c with (c>>2)==eg; eg==0 (waves 0,1) loss + idx. ---
    const int erow = tid & 127;
    const int eg   = tid >> 7;          // 0..3

    float best = smv[erow]; int bi = smi[erow];
#pragma unroll
    for (int s2 = 1; s2 < 4; ++s2) {    // idx-aware merge: order-independent
        float v  = smv[s2 * ROWS + erow];
        int   ii = smi[s2 * ROWS + erow];
        if (v < best || (v == best && ii < bi)) { best = v; bi = ii; }
    }

    const float4* qe4    = (const float4*)(emb + ((size_t)bi << 6));
    const float4* zrow4e = (const float4*)(z + (blockRow + erow) * D);
    float s = 0.f;
    float* orow = out_zq + (blockRow + erow) * D;
#pragma unroll
    for (int c = 0; c < 16; ++c) {
        float4 q  = qe4[c];
        float4 zv = zrow4e[c];
        float d0 = q.x - zv.x, d1 = q.y - zv.y, d2 = q.z - zv.z, d3 = q.w - zv.w;
        s += d0*d0; s += d1*d1; s += d2*d2; s += d3*d3;
        if ((c >> 2) == eg) {            // each (row,chunk) stored exactly once
            // out_zq is d_out+1 (4B-aligned) -> dword stores.
            orow[4*c+0] = zv.x + d0; orow[4*c+1] = zv.y + d1;
            orow[4*c+2] = zv.z + d2; orow[4*c+3] = zv.w + d3;
        }
    }

    if (eg == 0) {                       // waves 0,1: rows [64w, 64w+64)
        out_idx[blockRow + erow] = (float)bi;
#pragma unroll
        for (int off = 32; off; off >>= 1) s += __shfl_down(s, off);
        if (lane == 0) atomicAdd(out_loss, s * loss_scale);  // 64-row partials
    }
}

extern "C" void kernel_launch(void* const* d_in, const int* in_sizes, int n_in,
                              void* d_out, int out_size, void* d_ws, size_t ws_size,
                              hipStream_t stream) {
    const float* z   = (const float*)d_in[0];
    const float* emb = (const float*)d_in[1];
    const int nz = in_sizes[0];          // 4194304
    const int N  = nz / D;               // 65536 rows

    float* out      = (float*)d_out;
    float* out_zq   = out + 1;
    float* out_idx  = out + 1 + (size_t)nz;
    float* ee_ws    = (float*)d_ws;      // 4 KB

    const float loss_scale = 1.25f / (float)nz;

    hipMemsetAsync(out, 0, sizeof(float), stream);  // loss accumulator
    ee_kernel<<<NE / 64, 64, 0, stream>>>(emb, ee_ws);
    vq_kernel<<<N / ROWS, TPB, 0, stream>>>(z, emb, ee_ws, out, out_zq, out_idx,
                                            loss_scale);
}

// Round 16
// 211.023 us; speedup vs baseline: 1.1249x; 1.1249x over previous
//
#include <hip/hip_runtime.h>

// VQ-VAE quantizer: z [16,4096,64] f32, embedding [1024,64] f32.
// Outputs concatenated in d_out (float32): [0]=loss, [1..4194304]=z_q,
// [4194305..]=argmin indices (as float).
//
// Correctness-critical (verified absmax 0.0 through R15): per-(row,code)
// d = fmaf(-2,dot,(zz+ee)); dot accumulated as p0..p3 (acc.xyzw) over 16
// float4 chunks combined (p0+p1)+(p2+p3); zz/ee numpy-pairwise 8-accumulator
// tree, fp-contract OFF; first-index argmin via strict < on in-lane ascending
// scans + (val==, idx<) tie-break on every tree merge. Loss: per-row
// sequential col sum + 64-lane shfl tree + one atomic/block (R1 epilogue).
//
// R16 (final): revert to R11 -- the verified best (173.9us kernel, 212.6us
// bench, VGPR 128, WRITE 16.7MB clean) -- and drop one dispatch: ee_kernel
// zeroes the loss accumulator (it completes before vq_kernel on the same
// stream), removing hipMemsetAsync. The ~174us plateau survived six
// structural attacks (occupancy x2, LDS-ops -25%, pipe-split, 8x8 tile,
// addr strength-reduction, barrier-halving): LDS delivery floor ~128us +
// fmaf 55us + ~46us in-order issue slop is this algorithm's practical HIP
// floor under the bitwise-argmin constraint (distances at magnitude ~64
// have best-vs-second gaps below fp32 ulp across 65K rows -> any fp
// reordering, incl. MFMA, flips indices).

#define D 64
#define NE 1024
#define ROWS 64              // rows per block
#define TCODES 128           // codes per LDS tile
#define NTILES 8
#define TPB 256              // 4 waves = 4 code-quarters of each tile
#define ZSTR 64              // unpadded; XOR swizzle handles banks

// swizzled float index of (row, f4col c): row*64 + (c^(row&7))*4
#define SWZ(row, c) (((row) << 6) + ((((c) ^ ((row) & 7))) << 2))

__global__ __launch_bounds__(64, 4) void ee_kernel(const float* __restrict__ emb,
                                                   float* __restrict__ ee_ws,
                                                   float* __restrict__ out_loss) {
    if (blockIdx.x == 0 && threadIdx.x == 0) *out_loss = 0.0f;  // replaces memset
    const int j = blockIdx.x * 64 + threadIdx.x;   // 16 blocks x 64 = 1024 codes
    {
#pragma clang fp contract(off)
        const float4* e4 = (const float4*)(emb + ((size_t)j << 6));
        float4 a = e4[0], b = e4[1];
        float r[8];
        r[0]=a.x*a.x; r[1]=a.y*a.y; r[2]=a.z*a.z; r[3]=a.w*a.w;
        r[4]=b.x*b.x; r[5]=b.y*b.y; r[6]=b.z*b.z; r[7]=b.w*b.w;
#pragma unroll
        for (int g = 1; g < 8; ++g) {
            float4 c = e4[2*g], e = e4[2*g + 1];
            r[0]=r[0]+c.x*c.x; r[1]=r[1]+c.y*c.y;
            r[2]=r[2]+c.z*c.z; r[3]=r[3]+c.w*c.w;
            r[4]=r[4]+e.x*e.x; r[5]=r[5]+e.y*e.y;
            r[6]=r[6]+e.z*e.z; r[7]=r[7]+e.w*e.w;
        }
        ee_ws[j] = ((r[0]+r[1])+(r[2]+r[3])) + ((r[4]+r[5])+(r[6]+r[7]));
    }
}

__global__ __launch_bounds__(TPB, 2) void vq_kernel(const float* __restrict__ z,
                                                    const float* __restrict__ emb,
                                                    const float* __restrict__ ee_ws,
                                                    float* __restrict__ out_loss,
                                                    float* __restrict__ out_zq,
                                                    float* __restrict__ out_idx,
                                                    float loss_scale) {
    __shared__ __align__(16) float z_lds[ROWS * ZSTR];      // 16 KB
    __shared__ __align__(16) float e_lds[TCODES * ZSTR];    // 32 KB
    __shared__ float ee_lds[NE];                            // 4 KB
    __shared__ float zz_lds[ROWS];
    __shared__ float smv[4 * ROWS];
    __shared__ int   smi[4 * ROWS];

    const int tid  = threadIdx.x;
    const int lane = tid & 63;
    const int w    = tid >> 6;          // wave id = code quarter of each tile
    const int i8   = lane & 7;          // row group: rows i8 + 8rr (rr 0..7)
    const int jg   = lane >> 3;         // code group: codes 32w + jg + 8cc
    const size_t blockRow = (size_t)blockIdx.x * ROWS;

    // --- Stage z tile (64x64) into swizzled LDS (1024 f4, 4/thread). ---
    {
        const float4* zg4 = (const float4*)(z + blockRow * D);
#pragma unroll
        for (int it = 0; it < 4; ++it) {
            int idx = tid + it * TPB;
            float4 v = zg4[idx];
            *(float4*)&z_lds[SWZ(idx >> 4, idx & 15)] = v;
        }
    }
    // --- ee table from workspace (bit-identical, precomputed once). ---
    {
        float4 v = ((const float4*)ee_ws)[tid];
        *(float4*)&ee_lds[tid * 4] = v;
    }
    // --- Prefetch e-tile 0 into registers (32 KB, 8 f4/thread). ---
    float4 pe0, pe1, pe2, pe3, pe4, pe5, pe6, pe7;
    {
        const float4* eg4 = (const float4*)emb;
        pe0 = eg4[tid];        pe1 = eg4[tid + 256];
        pe2 = eg4[tid + 512];  pe3 = eg4[tid + 768];
        pe4 = eg4[tid + 1024]; pe5 = eg4[tid + 1280];
        pe6 = eg4[tid + 1536]; pe7 = eg4[tid + 1792];
    }
    __syncthreads();   // z_lds, ee_lds ready

    // --- zz per row (verified numpy tree) from the staged z bits. ---
    if (tid < ROWS) {
        float zr[D];
#pragma unroll
        for (int c = 0; c < 16; ++c) {
            float4 v = *(const float4*)&z_lds[SWZ(tid, c)];
            zr[4*c+0]=v.x; zr[4*c+1]=v.y; zr[4*c+2]=v.z; zr[4*c+3]=v.w;
        }
        {
#pragma clang fp contract(off)
            float r[8];
#pragma unroll
            for (int jj = 0; jj < 8; ++jj) { float t = zr[jj]*zr[jj]; r[jj] = t; }
#pragma unroll
            for (int i = 8; i < 64; i += 8) {
#pragma unroll
                for (int jj = 0; jj < 8; ++jj) { float t = zr[i+jj]*zr[i+jj]; r[jj] = r[jj] + t; }
            }
            zz_lds[tid] = ((r[0]+r[1])+(r[2]+r[3])) + ((r[4]+r[5])+(r[6]+r[7]));
        }
    }
    // (zz_lds becomes visible to all at the first in-loop barrier.)

    float rb[8];  int rbj[8];
#pragma unroll
    for (int rr = 0; rr < 8; ++rr) { rb[rr] = __builtin_inff(); rbj[rr] = 0; }

    // --- Main loop: 8 tiles of 128 codes; 2 barriers/tile. ---
    for (int t = 0; t < NTILES; ++t) {
        // Write prefetched tile t into LDS.
        *(float4*)&e_lds[SWZ((tid       ) >> 4, (tid       ) & 15)] = pe0;
        *(float4*)&e_lds[SWZ((tid +  256) >> 4, (tid +  256) & 15)] = pe1;
        *(float4*)&e_lds[SWZ((tid +  512) >> 4, (tid +  512) & 15)] = pe2;
        *(float4*)&e_lds[SWZ((tid +  768) >> 4, (tid +  768) & 15)] = pe3;
        *(float4*)&e_lds[SWZ((tid + 1024) >> 4, (tid + 1024) & 15)] = pe4;
        *(float4*)&e_lds[SWZ((tid + 1280) >> 4, (tid + 1280) & 15)] = pe5;
        *(float4*)&e_lds[SWZ((tid + 1536) >> 4, (tid + 1536) & 15)] = pe6;
        *(float4*)&e_lds[SWZ((tid + 1792) >> 4, (tid + 1792) & 15)] = pe7;
        __syncthreads();   // e tile t (and, at t=0, zz_lds) ready

        // Issue prefetch of tile t+1; latency hides under compute of tile t.
        if (t < NTILES - 1) {
            const float4* eg4 = (const float4*)(emb + (size_t)(t + 1) * TCODES * D);
            pe0 = eg4[tid];        pe1 = eg4[tid + 256];
            pe2 = eg4[tid + 512];  pe3 = eg4[tid + 768];
            pe4 = eg4[tid + 1024]; pe5 = eg4[tid + 1280];
            pe6 = eg4[tid + 1536]; pe7 = eg4[tid + 1792];
        }

        // 8 rows x 4 codes per lane; p0..p3 live in acc.{x,y,z,w} (verified order).
        float4 acc[8][4];
#pragma unroll
        for (int rr = 0; rr < 8; ++rr)
#pragma unroll
            for (int cc = 0; cc < 4; ++cc)
                acc[rr][cc] = make_float4(0.f, 0.f, 0.f, 0.f);

#pragma unroll 2
        for (int c = 0; c < 16; ++c) {
            float4 zf[8], ef[4];
#pragma unroll
            for (int rr = 0; rr < 8; ++rr)
                zf[rr] = *(const float4*)&z_lds[SWZ(i8 + 8*rr, c)];
#pragma unroll
            for (int cc = 0; cc < 4; ++cc)
                ef[cc] = *(const float4*)&e_lds[SWZ((w << 5) + jg + (cc << 3), c)];
#pragma unroll
            for (int rr = 0; rr < 8; ++rr)
#pragma unroll
                for (int cc = 0; cc < 4; ++cc) {
                    acc[rr][cc].x = fmaf(zf[rr].x, ef[cc].x, acc[rr][cc].x);
                    acc[rr][cc].y = fmaf(zf[rr].y, ef[cc].y, acc[rr][cc].y);
                    acc[rr][cc].z = fmaf(zf[rr].z, ef[cc].z, acc[rr][cc].z);
                    acc[rr][cc].w = fmaf(zf[rr].w, ef[cc].w, acc[rr][cc].w);
                }
        }

        // Fold: codes cbase + 8cc ascend with cc; tiles ascend with t -> strict <.
        const int cbase = t * TCODES + (w << 5) + jg;
        const float ee0 = ee_lds[cbase];
        const float ee1 = ee_lds[cbase + 8];
        const float ee2 = ee_lds[cbase + 16];
        const float ee3 = ee_lds[cbase + 24];
#pragma unroll
        for (int rr = 0; rr < 8; ++rr) {
            const float zzv = zz_lds[i8 + 8*rr];
            float dot0 = (acc[rr][0].x + acc[rr][0].y) + (acc[rr][0].z + acc[rr][0].w);
            float dot1 = (acc[rr][1].x + acc[rr][1].y) + (acc[rr][1].z + acc[rr][1].w);
            float dot2 = (acc[rr][2].x + acc[rr][2].y) + (acc[rr][2].z + acc[rr][2].w);
            float dot3 = (acc[rr][3].x + acc[rr][3].y) + (acc[rr][3].z + acc[rr][3].w);
            float d0 = fmaf(-2.0f, dot0, zzv + ee0);   // mirrors np (zz+ee) rounding
            float d1 = fmaf(-2.0f, dot1, zzv + ee1);
            float d2 = fmaf(-2.0f, dot2, zzv + ee2);
            float d3 = fmaf(-2.0f, dot3, zzv + ee3);
            float cv = d0; int cj = cbase;
            if (d1 < cv) { cv = d1; cj = cbase + 8;  }
            if (d2 < cv) { cv = d2; cj = cbase + 16; }
            if (d3 < cv) { cv = d3; cj = cbase + 24; }
            if (cv < rb[rr]) { rb[rr] = cv; rbj[rr] = cj; }
        }
        __syncthreads();   // all reads of e_lds done before next overwrite
    }

    // --- 3-step butterfly over jg (lane bits 3..5): tie -> smaller index. ---
#pragma unroll
    for (int rr = 0; rr < 8; ++rr) {
        float bv = rb[rr]; int bj = rbj[rr];
#pragma unroll
        for (int off = 8; off <= 32; off <<= 1) {
            float ov = __shfl_xor(bv, off);
            int   oi = __shfl_xor(bj, off);
            if (ov < bv || (ov == bv && oi < bj)) { bv = ov; bj = oi; }
        }
        if (jg == 0) {
            smv[w * ROWS + i8 + 8*rr] = bv;
            smi[w * ROWS + i8 + 8*rr] = bj;
        }
    }
    __syncthreads();

    // --- Epilogue (verified structure): thread handles row erow; wave eg
    //     stores f4-chunks c with (c>>2)==eg; wave 0 does loss + idx. ---
    const int erow = tid & 63;
    const int eg   = tid >> 6;

    float best = smv[erow]; int bi = smi[erow];
#pragma unroll
    for (int s2 = 1; s2 < 4; ++s2) {           // ascending code-quarter merge
        float v  = smv[s2 * ROWS + erow];
        int   ii = smi[s2 * ROWS + erow];
        if (v < best || (v == best && ii < bi)) { best = v; bi = ii; }
    }

    const float4* qe4 = (const float4*)(emb + ((size_t)bi << 6));
    float s = 0.f;
    float* orow = out_zq + (blockRow + erow) * D;
#pragma unroll
    for (int c = 0; c < 16; ++c) {
        float4 q  = qe4[c];
        float4 zv = *(const float4*)&z_lds[SWZ(erow, c)];
        float d0 = q.x - zv.x, d1 = q.y - zv.y, d2 = q.z - zv.z, d3 = q.w - zv.w;
        s += d0*d0; s += d1*d1; s += d2*d2; s += d3*d3;
        if ((c >> 2) == eg) {                  // each (row,chunk) stored once
            // out_zq is d_out+1 (4B-aligned) -> dword stores.
            orow[4*c+0] = zv.x + d0; orow[4*c+1] = zv.y + d1;
            orow[4*c+2] = zv.z + d2; orow[4*c+3] = zv.w + d3;
        }
    }

    if (eg == 0) {                             // wave 0: loss + idx
        out_idx[blockRow + erow] = (float)bi;
#pragma unroll
        for (int off = 32; off; off >>= 1) s += __shfl_down(s, off);
        if (tid == 0) atomicAdd(out_loss, s * loss_scale);
    }
}

extern "C" void kernel_launch(void* const* d_in, const int* in_sizes, int n_in,
                              void* d_out, int out_size, void* d_ws, size_t ws_size,
                              hipStream_t stream) {
    const float* z   = (const float*)d_in[0];
    const float* emb = (const float*)d_in[1];
    const int nz = in_sizes[0];          // 4194304
    const int N  = nz / D;               // 65536 rows

    float* out      = (float*)d_out;
    float* out_zq   = out + 1;
    float* out_idx  = out + 1 + (size_t)nz;
    float* ee_ws    = (float*)d_ws;      // 4 KB

    const float loss_scale = 1.25f / (float)nz;

    // ee_kernel also zeroes the loss accumulator (same-stream ordering
    // guarantees it completes before vq_kernel's atomics) -> no memset dispatch.
    ee_kernel<<<NE / 64, 64, 0, stream>>>(emb, ee_ws, out);
    vq_kernel<<<N / ROWS, TPB, 0, stream>>>(z, emb, ee_ws, out, out_zq, out_idx,
                                            loss_scale);
}